// Round 8
// baseline (63.724 us; speedup 1.0000x reference)
//
#include <hip/hip_runtime.h>
#include <math.h>

#define S 76
#define A 3
#define CH 85            // 5 + 80
#define MAXGT 150
#define CPB (S * S * A)              // 17328 cells per batch
#define FPB (CPB * CH)               // 1472880 floats per batch
#define BATCH 16
#define TILE 64                      // cells per block
#define BLK 256
#define N4F (TILE * CH / 4)          // 1360 float4 per full block
#define GX ((CPB + TILE - 1) / TILE) // 271 blocks per batch (last has 48 cells)
#define NBLK (GX * BATCH)            // 4336

__device__ __forceinline__ float frcp(float x) { return __builtin_amdgcn_rcpf(x); }
__device__ __forceinline__ float sigmoidf_(float x) { return frcp(1.f + __expf(-x)); }
// bce_with_logits(x,y) = ln(1+e^x) - x*y   (safe for |x| < ~80)
__device__ __forceinline__ float bcef(float x, float y) {
    const float t  = __builtin_amdgcn_exp2f(x * 1.44269504f);
    const float lg = __builtin_amdgcn_logf(1.f + t);            // log2(1+e^x)
    return __builtin_fmaf(0.69314718f, lg, -x * y);
}

// One block = 64 cells of one batch. Phase 1: coalesced stream of the block's
// conv+label range (the ONLY bulk global traffic) computing prob-BCE and
// staging header channels to LDS. Phase 2: geo losses purely from LDS.
__global__ __launch_bounds__(BLK) void yolo_unified_kernel(
    const float* __restrict__ conv, const float* __restrict__ label,
    const float* __restrict__ bboxes, float* __restrict__ part)
{
    __shared__ float  s_ch[TILE][5];   // conv header: dx,dy,dw,dh,rawconf
    __shared__ float  s_lh[TILE][5];   // label header: x,y,w,h,resp
    __shared__ float  s_resp[TILE];
    __shared__ float4 s_box[MAXGT];    // 3*x1, y1, 3*x2, y2
    __shared__ float  s_ba[MAXGT];
    __shared__ float  sred[3][BLK / 64];

    const int b   = blockIdx.y;
    const int tid = threadIdx.x;
    const int base_cell = blockIdx.x * TILE;
    const int ncells = min(TILE, CPB - base_cell);
    const int n4 = (ncells * CH) >> 2;          // 1360 full / 1020 tail (both exact)

    const size_t eb = (size_t)b * FPB + (size_t)base_cell * CH;   // multiple of 4
    const float*  lbb = label + eb;
    const float4* cv4 = (const float4*)(conv + eb);
    const float4* lb4 = (const float4*)lbb;

    // ---- phase 0: boxes -> LDS; resp preload (lines re-hit by the stream) ----
    if (tid < MAXGT) {
        const float4 bx = *(const float4*)(bboxes + (size_t)b * (MAXGT * 4) + tid * 4);
        const float hw = bx.z * 0.5f, hh = bx.w * 0.5f;
        s_box[tid] = make_float4(3.f * (bx.x - hw), bx.y - hh, 3.f * (bx.x + hw), bx.y + hh);
        s_ba[tid]  = bx.z * bx.w;
    }
    if (tid < TILE)
        s_resp[tid] = (tid < ncells) ? lbb[(size_t)tid * CH + 4] : 0.f;
    __syncthreads();

    // ---- phase 1: coalesced stream + header staging ----
    float p_sum = 0.f;
    auto body = [&](int u) {
        const float4 cc = cv4[u];
        const float4 lc = lb4[u];
        const unsigned e0 = 4u * (unsigned)u;
        const unsigned c0 = e0 / 85u;            // magic-mul
        const unsigned r0 = e0 - 85u * c0;
        const float rsp = s_resp[c0];
        const float cx[4] = {cc.x, cc.y, cc.z, cc.w};
        const float lx[4] = {lc.x, lc.y, lc.z, lc.w};
        float s = 0.f;
        #pragma unroll
        for (int k = 0; k < 4; ++k) {
            const unsigned rr = r0 + (unsigned)k;        // [0,87]
            const float bv = bcef(cx[k], lx[k]);
            s += ((rr - 5u) < 80u) ? bv : 0.f;           // class channels of cell c0
            const bool hdr = (rr < 5u) || (rr >= 85u);   // header of c0 or c0+1
            if (hdr) {
                const unsigned cell = (rr < 5u) ? c0 : c0 + 1u;
                const unsigned chn  = (rr < 5u) ? rr : rr - 85u;
                s_ch[cell][chn] = cx[k];
                s_lh[cell][chn] = lx[k];
            }
        }
        p_sum = __builtin_fmaf(rsp, s, p_sum);
    };
    if (n4 == N4F) {
        #pragma unroll
        for (int r = 0; r < N4F / BLK; ++r) body(r * BLK + tid);         // 5 full rounds
        if (tid < (N4F - (N4F / BLK) * BLK)) body((N4F / BLK) * BLK + tid); // 80 thr
    } else {
        for (int u = tid; u < n4; u += BLK) body(u);
    }
    __syncthreads();

    // ---- phase 2: geo from LDS only; 4 threads per cell ----
    const int c = tid >> 2;          // cell within tile
    const int q = tid & 3;           // quarter of the box list
    float g_sum = 0.f, c_sum = 0.f;
    if (c < ncells) {
        const int t   = base_cell + c;
        const int i   = t / (S * A);
        const int rem = t - i * (S * A);
        const int j   = rem / A;
        const int a   = rem - j * A;
        const float aw = (a == 0) ? 12.f : ((a == 1) ? 19.f : 40.f);
        const float ah = (a == 0) ? 16.f : ((a == 1) ? 36.f : 28.f);

        const float dx = s_ch[c][0], dy = s_ch[c][1], dw = s_ch[c][2],
                    dh = s_ch[c][3], rc = s_ch[c][4];
        const float lxc = s_lh[c][0], lyc = s_lh[c][1], lwc = s_lh[c][2],
                    lhc = s_lh[c][3], resp = s_lh[c][4];

        const float px = (sigmoidf_(dx) * 1.2f - 0.1f + (float)j) * 8.f;
        const float py = (sigmoidf_(dy) * 1.2f - 0.1f + (float)i) * 8.f;
        const float pw = __expf(dw) * aw;
        const float ph = __expf(dh) * ah;
        const float pconf = sigmoidf_(rc);

        const float px1 = px - pw * 0.5f, py1 = py - ph * 0.5f;
        const float px2 = px + pw * 0.5f, py2 = py + ph * 0.5f;
        const float areap = pw * ph;

        // max_iou<0.5  <=>  max_k(3*inter_k - area_k) < area_p  (division-free)
        const float px1_3 = 3.f * px1, px2_3 = 3.f * px2;
        float maxv = -1e30f;
        #pragma unroll 5
        for (int k = q; k < MAXGT; k += 4) {             // 38/37 iters
            const float4 bx = s_box[k];
            const float ba  = s_ba[k];
            const float kiw3 = fmaxf(fminf(px2_3, bx.z) - fmaxf(px1_3, bx.x), 0.f);
            const float kih  = fmaxf(fminf(py2, bx.w) - fmaxf(py1, bx.y), 0.f);
            maxv = fmaxf(maxv, __builtin_fmaf(kiw3, kih, -ba));
        }
        maxv = fmaxf(maxv, __shfl_xor(maxv, 1, 64));
        maxv = fmaxf(maxv, __shfl_xor(maxv, 2, 64));

        if (q == 0) {
            const float lx1 = lxc - lwc * 0.5f, ly1 = lyc - lhc * 0.5f;
            const float lx2 = lxc + lwc * 0.5f, ly2 = lyc + lhc * 0.5f;
            const float areal = lwc * lhc;
            const float iw = fmaxf(fminf(px2, lx2) - fmaxf(px1, lx1), 0.f);
            const float ih = fmaxf(fminf(py2, ly2) - fmaxf(py1, ly1), 0.f);
            const float inter = iw * ih;
            const float uni = areap + areal - inter;
            const float iou = inter * frcp(uni);
            const float ew = fmaxf(fmaxf(px2, lx2) - fminf(px1, lx1), 0.f);
            const float eh = fmaxf(fmaxf(py2, ly2) - fminf(py1, ly1), 0.f);
            const float enc = ew * eh;
            const float giou = iou - (enc - uni) * frcp(enc);
            g_sum = resp * (2.f - areal * (1.f / (608.f * 608.f))) * (1.f - giou);

            const float bgd = (1.f - resp) * ((maxv < areap) ? 1.f : 0.f);
            const float focal = (resp - pconf) * (resp - pconf);
            c_sum = focal * (resp + bgd) * bcef(rc, resp);
        }
    }

    // ---- block reduction (3 values) ----
    for (int off = 32; off > 0; off >>= 1) {
        g_sum += __shfl_down(g_sum, off, 64);
        c_sum += __shfl_down(c_sum, off, 64);
        p_sum += __shfl_down(p_sum, off, 64);
    }
    const int lane = tid & 63, wv = tid >> 6;
    if (lane == 0) { sred[0][wv] = g_sum; sred[1][wv] = c_sum; sred[2][wv] = p_sum; }
    __syncthreads();
    if (tid == 0) {
        float G = 0.f, C = 0.f, P = 0.f;
        #pragma unroll
        for (int w = 0; w < BLK / 64; ++w) { G += sred[0][w]; C += sred[1][w]; P += sred[2][w]; }
        const int bid = blockIdx.y * gridDim.x + blockIdx.x;
        part[bid * 3 + 0] = G;
        part[bid * 3 + 1] = C;
        part[bid * 3 + 2] = P;
    }
}

// ---------------- final deterministic reduce ----------------
__global__ __launch_bounds__(256) void final_reduce(
    const float* __restrict__ part, float* __restrict__ out, int nblocks, float invB)
{
    const int tid = threadIdx.x;
    float g = 0.f, c = 0.f, p = 0.f;
    for (int k = tid; k < nblocks; k += 256) {
        g += part[3 * k + 0];
        c += part[3 * k + 1];
        p += part[3 * k + 2];
    }
    for (int off = 32; off > 0; off >>= 1) {
        g += __shfl_down(g, off, 64);
        c += __shfl_down(c, off, 64);
        p += __shfl_down(p, off, 64);
    }
    __shared__ float sred[3][4];
    const int lane = tid & 63, wv = tid >> 6;
    if (lane == 0) { sred[0][wv] = g; sred[1][wv] = c; sred[2][wv] = p; }
    __syncthreads();
    if (tid == 0) {
        float G = 0.f, C = 0.f, P = 0.f;
        #pragma unroll
        for (int w = 0; w < 4; ++w) { G += sred[0][w]; C += sred[1][w]; P += sred[2][w]; }
        out[0] = G * invB;
        out[1] = C * invB;
        out[2] = P * invB;
    }
}

extern "C" void kernel_launch(void* const* d_in, const int* in_sizes, int n_in,
                              void* d_out, int out_size, void* d_ws, size_t ws_size,
                              hipStream_t stream) {
    const float* conv   = (const float*)d_in[0];
    const float* label  = (const float*)d_in[1];
    const float* bboxes = (const float*)d_in[2];
    float* out  = (float*)d_out;
    float* part = (float*)d_ws;          // NBLK*3 = 13008 floats

    dim3 grid(GX, BATCH);
    yolo_unified_kernel<<<grid, BLK, 0, stream>>>(conv, label, bboxes, part);
    final_reduce<<<1, 256, 0, stream>>>(part, out, NBLK, 1.f / (float)BATCH);
}